// Round 1
// baseline (1526.910 us; speedup 1.0000x reference)
//
#include <hip/hip_runtime.h>
#include <cstdint>

#define Bn 64
#define Hn 1024
#define Sn 512
#define Vn 50257

typedef short short8 __attribute__((ext_vector_type(8)));
typedef float f32x4 __attribute__((ext_vector_type(4)));

__device__ inline float fast_exp2(float x){ return __builtin_amdgcn_exp2f(x); }
__device__ inline float fast_rcp(float x){ return __builtin_amdgcn_rcpf(x); }
__device__ inline float fast_tanh(float x){
  // tanh(x) = 1 - 2/(exp2(2*log2e*x)+1); saturates correctly for |x| large
  float e = fast_exp2(x * 2.8853900817779268f);
  return 1.0f - 2.0f*fast_rcp(e + 1.0f);
}
__device__ inline float fast_sigmoid(float x){
  return fast_rcp(1.0f + fast_exp2(-1.4426950408889634f*x));
}
__device__ inline unsigned int bf16rne(float f){
  unsigned int u = __float_as_uint(f);
  return (u + 0x7fffu + ((u>>16)&1u)) >> 16;
}
__device__ inline unsigned int bfpack(float lo, float hi){
  return bf16rne(lo) | (bf16rne(hi) << 16);
}

// ---------------- prep: gather x = emb[idx] and transpose x,h0 to [k/4][b][4] ----------------
__global__ void prep_kernel(const int* __restrict__ idx, const float4* __restrict__ emb,
                            const float4* __restrict__ h0, float4* __restrict__ xT4,
                            float4* __restrict__ hT4){
  int b = blockIdx.x; int t = threadIdx.x; // 256 threads, one float4 (4 k) each
  int row = idx[b];
  xT4[t*64 + b] = emb[(long)row*256 + t];
  hT4[t*64 + b] = h0[b*256 + t];
}

// ---------------- convert We = W_attn[:, H:] to bf16 [g][k] ----------------
__global__ void conv_we_kernel(const float* __restrict__ W_attn, unsigned short* __restrict__ we){
  int id0 = blockIdx.x*1024 + threadIdx.x;
  #pragma unroll
  for (int i=0;i<4;i++){
    int id = id0 + i*256;
    int g = id >> 10, k = id & 1023;
    we[id] = (unsigned short)bf16rne(W_attn[g*2048 + 1024 + k]);
  }
}

__global__ void zero_kernel(float* __restrict__ p, int n){
  int id = blockIdx.x*256 + threadIdx.x;
  if (id < n) p[id] = 0.f;
}

// ---------------- skinny GEMM: out[b][n] = act(sum_k AT[k][b]*W[n][k] + bias) ----------------
// AT is [K/4][64][4] float (float4 per lane). W rows are uniform -> scalar loads.
template<int TN, int NM, bool DOTANH, bool OUTT4>
__global__ void skinny_gemm(const float4* __restrict__ A0, const float* __restrict__ W0, int w0s,
                            const float4* __restrict__ A1, const float* __restrict__ W1, int w1s, int w1o,
                            const float* __restrict__ bias0, const float* __restrict__ bias1,
                            float* __restrict__ out, int N, long outStride, int K4)
{
  int tid = threadIdx.x; int l = tid & 63; int w = tid >> 6;
  int n0 = __builtin_amdgcn_readfirstlane(blockIdx.x*(4*TN) + w*TN);
  float acc[TN];
  #pragma unroll
  for (int j=0;j<TN;j++) acc[j]=0.f;
  int nr[TN];
  #pragma unroll
  for (int j=0;j<TN;j++){ int n=n0+j; nr[j] = (n < N) ? n : (N-1); }
  for (int k4=0;k4<K4;k4++){
    float4 a = A0[k4*64 + l];
    #pragma unroll
    for (int j=0;j<TN;j++){
      const float* wr = W0 + (long)nr[j]*w0s + k4*4;
      acc[j] = fmaf(a.x, wr[0], acc[j]);
      acc[j] = fmaf(a.y, wr[1], acc[j]);
      acc[j] = fmaf(a.z, wr[2], acc[j]);
      acc[j] = fmaf(a.w, wr[3], acc[j]);
    }
    if constexpr (NM==2){
      float4 a1 = A1[k4*64 + l];
      #pragma unroll
      for (int j=0;j<TN;j++){
        const float* wr = W1 + (long)nr[j]*w1s + w1o + k4*4;
        acc[j] = fmaf(a1.x, wr[0], acc[j]);
        acc[j] = fmaf(a1.y, wr[1], acc[j]);
        acc[j] = fmaf(a1.z, wr[2], acc[j]);
        acc[j] = fmaf(a1.w, wr[3], acc[j]);
      }
    }
  }
  #pragma unroll
  for (int j=0;j<TN;j++){
    int n = n0+j;
    if (n >= N) break;
    float v = acc[j];
    if (bias0) v += bias0[n];
    if (bias1) v += bias1[n];
    if (DOTANH) v = fast_tanh(v);
    if (OUTT4) out[(n>>2)*256 + l*4 + (n&3)] = v;
    else       out[(long)l*outStride + n] = v;
  }
}

// ---------------- LSTM elementwise ----------------
__global__ void lstm_kernel(const float* __restrict__ gates, const float* __restrict__ c0,
                            float* __restrict__ h_out, float* __restrict__ c_out,
                            float* __restrict__ hT4){
  int id = blockIdx.x*256 + threadIdx.x; // 65536
  int b = id >> 10, h = id & 1023;
  const float* g = gates + (long)b*4096;
  float vi = g[h], vf = g[1024+h], vg = g[2048+h], vo = g[3072+h];
  float cp = c0[id];
  float cn = fast_sigmoid(vf)*cp + fast_sigmoid(vi)*fast_tanh(vg);
  float hn = fast_sigmoid(vo)*fast_tanh(cn);
  c_out[id] = cn; h_out[id] = hn;
  hT4[(h>>2)*256 + b*4 + (h&3)] = hn;
}

// ---------------- energy GEMM + tanh + v-dot, MFMA bf16 ----------------
// grid 2048: XCD-swizzled (s, g-quarter). scoresT[s*64+b] accumulated via atomicAdd.
__launch_bounds__(256, 2)
__global__ void attn_scores_kernel(const float4* __restrict__ enc, const unsigned short* __restrict__ we,
                                   const float* __restrict__ hWh, const float* __restrict__ vattn,
                                   float* __restrict__ scoresT)
{
  __shared__ unsigned short Asb[64*40];   // 64 rows (b) x 32 k bf16, stride 40
  __shared__ unsigned short Bsb[256*40];  // 256 rows (g) x 32 k bf16, stride 40
  int tid = threadIdx.x;
  int bid = blockIdx.x;
  int xcd = bid & 7, slot = bid >> 3;
  int s  = xcd*64 + (slot >> 2);
  int g0 = (slot & 3) * 256;
  int l = tid & 63, w = tid >> 6;
  int quad = l >> 4, l15 = l & 15;

  int arow = tid >> 2, aq = tid & 3;
  long abase = ((long)s*64 + arow)*256;   // float4 index of enc row start

  f32x4 acc[4][4];
  #pragma unroll
  for (int mt=0;mt<4;mt++)
    #pragma unroll
    for (int gt=0;gt<4;gt++) acc[mt][gt] = 0.f;

  for (int kt=0; kt<32; kt++){
    __syncthreads();
    {
      // stage A: 64 rows x 32 k fp32 -> bf16 LDS
      float4 f0 = enc[abase + kt*8 + aq*2];
      float4 f1 = enc[abase + kt*8 + aq*2 + 1];
      uint4 p;
      p.x = bfpack(f0.x, f0.y); p.y = bfpack(f0.z, f0.w);
      p.z = bfpack(f1.x, f1.y); p.w = bfpack(f1.z, f1.w);
      *(uint4*)&Asb[arow*40 + aq*8] = p;
      // stage B: 256 rows (g) x 32 k bf16
      #pragma unroll
      for (int p4=0;p4<4;p4++){
        int grow = p4*64 + (tid>>2);
        const uint4* src = (const uint4*)&we[(long)(g0+grow)*1024 + kt*32 + aq*8];
        *(uint4*)&Bsb[grow*40 + aq*8] = *src;
      }
    }
    __syncthreads();
    short8 af[4], bfr[4];
    #pragma unroll
    for (int mt=0;mt<4;mt++) af[mt]  = *(const short8*)&Asb[(mt*16 + l15)*40 + quad*8];
    #pragma unroll
    for (int gt=0;gt<4;gt++) bfr[gt] = *(const short8*)&Bsb[(w*64 + gt*16 + l15)*40 + quad*8];
    #pragma unroll
    for (int mt=0;mt<4;mt++)
      #pragma unroll
      for (int gt=0;gt<4;gt++)
        acc[mt][gt] = __builtin_amdgcn_mfma_f32_16x16x32_bf16(af[mt], bfr[gt], acc[mt][gt], 0,0,0);
  }

  // epilogue: sp[row] += v[g]*tanh(hWh[b][g] + C[b][g])
  float sp[16];
  #pragma unroll
  for (int i=0;i<16;i++) sp[i]=0.f;
  #pragma unroll
  for (int gt=0;gt<4;gt++){
    int g = g0 + w*64 + gt*16 + l15;
    float vg = vattn[g];
    #pragma unroll
    for (int mt=0;mt<4;mt++){
      #pragma unroll
      for (int r=0;r<4;r++){
        int b = mt*16 + quad*4 + r;
        float val = acc[mt][gt][r] + hWh[b*1024 + g];
        sp[mt*4+r] = fmaf(vg, fast_tanh(val), sp[mt*4+r]);
      }
    }
  }
  #pragma unroll
  for (int off=1; off<16; off<<=1){
    #pragma unroll
    for (int i=0;i<16;i++) sp[i] += __shfl_xor(sp[i], off);
  }
  if (l15 == 0){
    #pragma unroll
    for (int mt=0;mt<4;mt++)
      #pragma unroll
      for (int r=0;r<4;r++){
        int b = mt*16 + quad*4 + r;
        atomicAdd(&scoresT[s*64 + b], sp[mt*4+r]);
      }
  }
}

// ---------------- softmax over b (axis=0) per s, apply mask ----------------
__global__ void softmax_b_kernel(float* __restrict__ a_sb, const float* __restrict__ mask){
  int tid = threadIdx.x; int l = tid & 63; int w = tid >> 6;
  int s = blockIdx.x*4 + w;
  float x = a_sb[s*64 + l];
  float m = x;
  #pragma unroll
  for (int off=1; off<64; off<<=1) m = fmaxf(m, __shfl_xor(m, off));
  float e = fast_exp2((x - m)*1.4426950408889634f);
  float t = e;
  #pragma unroll
  for (int off=1; off<64; off<<=1) t += __shfl_xor(t, off);
  float a = e * fast_rcp(t);
  a *= mask[s*64 + l];
  a_sb[s*64 + l] = a;
}

// ---------------- normalize over s per b; write alpha and aBS ----------------
__global__ void norm_s_kernel(const float* __restrict__ a_sb, float* __restrict__ aBS,
                              float* __restrict__ alpha){
  int b = blockIdx.x; int l = threadIdx.x; // 64 threads
  float tot = 0.f;
  #pragma unroll
  for (int i=0;i<8;i++) tot += a_sb[(l + i*64)*64 + b];
  #pragma unroll
  for (int off=1; off<64; off<<=1) tot += __shfl_xor(tot, off);
  float inv = 1.0f/(tot + 1e-10f);
  #pragma unroll
  for (int i=0;i<8;i++){
    int sidx = l + i*64;
    float v = a_sb[sidx*64 + b]*inv;
    aBS[b*512 + sidx] = v;
    alpha[b*512 + sidx] = v;
  }
}

// ---------------- context[b][h] = sum_s a[b][s]*enc[s][b][h] ----------------
__global__ void context_kernel(const float* __restrict__ aBS, const float* __restrict__ enc,
                               float* __restrict__ ctx_out, float* __restrict__ ctxT4){
  int h = blockIdx.x*256 + threadIdx.x;
  int b = blockIdx.y;
  const float* ab = aBS + b*512;
  float acc = 0.f;
  for (int s0=0; s0<512; s0+=16){
    float av[16], ev[16];
    #pragma unroll
    for (int i=0;i<16;i++) av[i] = ab[s0+i];
    #pragma unroll
    for (int i=0;i<16;i++) ev[i] = enc[((long)(s0+i)*64 + b)*1024 + h];
    #pragma unroll
    for (int i=0;i<16;i++) acc = fmaf(av[i], ev[i], acc);
  }
  ctx_out[b*1024 + h] = acc;
  ctxT4[(h>>2)*256 + b*4 + (h&3)] = acc;
}

extern "C" void kernel_launch(void* const* d_in, const int* in_sizes, int n_in,
                              void* d_out, int out_size, void* d_ws, size_t ws_size,
                              hipStream_t stream)
{
  const int*   idx    = (const int*)  d_in[0];
  const float* h0     = (const float*)d_in[2];
  const float* c0     = (const float*)d_in[3];
  const float* enc    = (const float*)d_in[4];
  const float* mask   = (const float*)d_in[5];
  const float* emb    = (const float*)d_in[6];
  const float* W_ih   = (const float*)d_in[7];
  const float* W_hh   = (const float*)d_in[8];
  const float* b_ih   = (const float*)d_in[9];
  const float* b_hh   = (const float*)d_in[10];
  const float* W_attn = (const float*)d_in[11];
  const float* v_attn = (const float*)d_in[12];
  const float* W_cat  = (const float*)d_in[13];
  const float* b_cat  = (const float*)d_in[14];
  const float* W_out  = (const float*)d_in[15];
  const float* b_out  = (const float*)d_in[16];

  float* out     = (float*)d_out;
  float* o_ctx   = out + (long)Bn*Vn;
  float* o_h     = o_ctx + Bn*Hn;
  float* o_c     = o_h + Bn*Hn;
  float* o_alpha = o_c + Bn*Hn;

  float* ws    = (float*)d_ws;
  float* xT4   = ws;               // 65536
  float* hT4   = xT4 + 65536;      // 65536
  float* gates = hT4 + 65536;      // 262144
  float* hnT4  = gates + 262144;   // 65536
  float* hWh   = hnT4 + 65536;     // 65536
  float* a_sb  = hWh + 65536;      // 32768 (scoresT, then softmaxed a)
  float* aBS   = a_sb + 32768;     // 32768
  float* ctxT4 = aBS + 32768;      // 65536
  float* catT4 = ctxT4 + 65536;    // 65536
  unsigned short* we_bf = (unsigned short*)(catT4 + 65536); // 1M bf16 = 2 MB

  prep_kernel<<<64,256,0,stream>>>(idx, (const float4*)emb, (const float4*)h0,
                                   (float4*)xT4, (float4*)hT4);
  conv_we_kernel<<<1024,256,0,stream>>>(W_attn, we_bf);
  zero_kernel<<<128,256,0,stream>>>(a_sb, 32768);
  // gates = x@W_ih^T + h@W_hh^T + b_ih + b_hh
  skinny_gemm<4,2,false,false><<<256,256,0,stream>>>((const float4*)xT4, W_ih, 1024,
      (const float4*)hT4, W_hh, 1024, 0, b_ih, b_hh, gates, 4096, 4096, 256);
  lstm_kernel<<<256,256,0,stream>>>(gates, c0, o_h, o_c, hnT4);
  // hWh[b][g] = h_new @ Wh^T  (Wh = W_attn[:, :H], row stride 2048)
  skinny_gemm<4,1,false,false><<<64,256,0,stream>>>((const float4*)hnT4, W_attn, 2048,
      nullptr, nullptr, 0, 0, nullptr, nullptr, hWh, 1024, 1024, 256);
  attn_scores_kernel<<<2048,256,0,stream>>>((const float4*)enc, we_bf, hWh, v_attn, a_sb);
  softmax_b_kernel<<<128,256,0,stream>>>(a_sb, mask);
  norm_s_kernel<<<64,64,0,stream>>>(a_sb, aBS, o_alpha);
  context_kernel<<<dim3(4,64),256,0,stream>>>(aBS, enc, o_ctx, ctxT4);
  // concat = tanh(h@Wc1^T + ctx@Wc2^T + b_cat), written transposed for vocab GEMM
  skinny_gemm<4,2,true,true><<<64,256,0,stream>>>((const float4*)hnT4, W_cat, 2048,
      (const float4*)ctxT4, W_cat, 2048, 1024, b_cat, nullptr, catT4, 1024, 0, 256);
  // output = concat@W_out^T + b_out
  skinny_gemm<8,1,false,false><<<1571,256,0,stream>>>((const float4*)catT4, W_out, 1024,
      nullptr, nullptr, 0, 0, b_out, nullptr, out, Vn, Vn, 256);
}

// Round 2
// 1208.846 us; speedup vs baseline: 1.2631x; 1.2631x over previous
//
#include <hip/hip_runtime.h>
#include <cstdint>

#define Bn 64
#define Hn 1024
#define Sn 512
#define Vn 50257

typedef short short8 __attribute__((ext_vector_type(8)));
typedef float f32x4 __attribute__((ext_vector_type(4)));

__device__ inline float fast_exp2(float x){ return __builtin_amdgcn_exp2f(x); }
__device__ inline float fast_rcp(float x){ return __builtin_amdgcn_rcpf(x); }
__device__ inline float fast_tanh(float x){
  float e = fast_exp2(x * 2.8853900817779268f);
  return 1.0f - 2.0f*fast_rcp(e + 1.0f);
}
__device__ inline float fast_sigmoid(float x){
  return fast_rcp(1.0f + fast_exp2(-1.4426950408889634f*x));
}
__device__ inline unsigned int bf16rne(float f){
  unsigned int u = __float_as_uint(f);
  return (u + 0x7fffu + ((u>>16)&1u)) >> 16;
}
__device__ inline unsigned int bfpack(float lo, float hi){
  return bf16rne(lo) | (bf16rne(hi) << 16);
}

// ---------------- prep: gather x = emb[idx] and transpose x,h0 to [k/4][b][4] ----------------
__global__ void prep_kernel(const int* __restrict__ idx, const float4* __restrict__ emb,
                            const float4* __restrict__ h0, float4* __restrict__ xT4,
                            float4* __restrict__ hT4){
  int b = blockIdx.x; int t = threadIdx.x;
  int row = idx[b];
  xT4[t*64 + b] = emb[(long)row*256 + t];
  hT4[t*64 + b] = h0[b*256 + t];
}

// ---------------- convert We = W_attn[:, H:] to bf16 [g][k] ----------------
__global__ void conv_we_kernel(const float* __restrict__ W_attn, unsigned short* __restrict__ we){
  int id0 = blockIdx.x*1024 + threadIdx.x;
  #pragma unroll
  for (int i=0;i<4;i++){
    int id = id0 + i*256;
    int g = id >> 10, k = id & 1023;
    we[id] = (unsigned short)bf16rne(W_attn[g*2048 + 1024 + k]);
  }
}

__global__ void zero_kernel(float* __restrict__ p, int n){
  int id = blockIdx.x*256 + threadIdx.x;
  if (id < n) p[id] = 0.f;
}

// ---------------- skinny GEMM (fp32 VALU, wave-uniform W rows) ----------------
template<int TN, int NM, bool DOTANH, bool OUTT4>
__global__ void skinny_gemm(const float4* __restrict__ A0, const float* __restrict__ W0, int w0s,
                            const float4* __restrict__ A1, const float* __restrict__ W1, int w1s, int w1o,
                            const float* __restrict__ bias0, const float* __restrict__ bias1,
                            float* __restrict__ out, int N, long outStride, int K4)
{
  int tid = threadIdx.x; int l = tid & 63; int w = tid >> 6;
  int n0 = __builtin_amdgcn_readfirstlane(blockIdx.x*(4*TN) + w*TN);
  float acc[TN];
  #pragma unroll
  for (int j=0;j<TN;j++) acc[j]=0.f;
  int nr[TN];
  #pragma unroll
  for (int j=0;j<TN;j++){ int n=n0+j; nr[j] = (n < N) ? n : (N-1); }
  for (int k4=0;k4<K4;k4++){
    float4 a = A0[k4*64 + l];
    #pragma unroll
    for (int j=0;j<TN;j++){
      const float4 wv = *(const float4*)(W0 + (long)nr[j]*w0s + k4*4);
      acc[j] = fmaf(a.x, wv.x, acc[j]);
      acc[j] = fmaf(a.y, wv.y, acc[j]);
      acc[j] = fmaf(a.z, wv.z, acc[j]);
      acc[j] = fmaf(a.w, wv.w, acc[j]);
    }
    if constexpr (NM==2){
      float4 a1 = A1[k4*64 + l];
      #pragma unroll
      for (int j=0;j<TN;j++){
        const float4 wv = *(const float4*)(W1 + (long)nr[j]*w1s + w1o + k4*4);
        acc[j] = fmaf(a1.x, wv.x, acc[j]);
        acc[j] = fmaf(a1.y, wv.y, acc[j]);
        acc[j] = fmaf(a1.z, wv.z, acc[j]);
        acc[j] = fmaf(a1.w, wv.w, acc[j]);
      }
    }
  }
  #pragma unroll
  for (int j=0;j<TN;j++){
    int n = n0+j;
    if (n >= N) break;
    float v = acc[j];
    if (bias0) v += bias0[n];
    if (bias1) v += bias1[n];
    if (DOTANH) v = fast_tanh(v);
    if (OUTT4) out[(n>>2)*256 + l*4 + (n&3)] = v;
    else       out[(long)l*outStride + n] = v;
  }
}

// ---------------- LSTM elementwise ----------------
__global__ void lstm_kernel(const float* __restrict__ gates, const float* __restrict__ c0,
                            float* __restrict__ h_out, float* __restrict__ c_out,
                            float* __restrict__ hT4){
  int id = blockIdx.x*256 + threadIdx.x;
  int b = id >> 10, h = id & 1023;
  const float* g = gates + (long)b*4096;
  float vi = g[h], vf = g[1024+h], vg = g[2048+h], vo = g[3072+h];
  float cp = c0[id];
  float cn = fast_sigmoid(vf)*cp + fast_sigmoid(vi)*fast_tanh(vg);
  float hn = fast_sigmoid(vo)*fast_tanh(cn);
  c_out[id] = cn; h_out[id] = hn;
  hT4[(h>>2)*256 + b*4 + (h&3)] = hn;
}

// ---------------- energy GEMM + tanh + v-dot, MFMA bf16 ----------------
__launch_bounds__(256, 2)
__global__ void attn_scores_kernel(const float4* __restrict__ enc, const unsigned short* __restrict__ we,
                                   const float* __restrict__ hWh, const float* __restrict__ vattn,
                                   float* __restrict__ scoresT)
{
  __shared__ unsigned short Asb[64*40];
  __shared__ unsigned short Bsb[256*40];
  int tid = threadIdx.x;
  int bid = blockIdx.x;
  int xcd = bid & 7, slot = bid >> 3;
  int s  = xcd*64 + (slot >> 2);
  int g0 = (slot & 3) * 256;
  int l = tid & 63, w = tid >> 6;
  int quad = l >> 4, l15 = l & 15;

  int arow = tid >> 2, aq = tid & 3;
  long abase = ((long)s*64 + arow)*256;

  f32x4 acc[4][4];
  #pragma unroll
  for (int mt=0;mt<4;mt++)
    #pragma unroll
    for (int gt=0;gt<4;gt++) acc[mt][gt] = 0.f;

  for (int kt=0; kt<32; kt++){
    __syncthreads();
    {
      float4 f0 = enc[abase + kt*8 + aq*2];
      float4 f1 = enc[abase + kt*8 + aq*2 + 1];
      uint4 p;
      p.x = bfpack(f0.x, f0.y); p.y = bfpack(f0.z, f0.w);
      p.z = bfpack(f1.x, f1.y); p.w = bfpack(f1.z, f1.w);
      *(uint4*)&Asb[arow*40 + aq*8] = p;
      #pragma unroll
      for (int p4=0;p4<4;p4++){
        int grow = p4*64 + (tid>>2);
        const uint4* src = (const uint4*)&we[(long)(g0+grow)*1024 + kt*32 + aq*8];
        *(uint4*)&Bsb[grow*40 + aq*8] = *src;
      }
    }
    __syncthreads();
    short8 af[4], bfr[4];
    #pragma unroll
    for (int mt=0;mt<4;mt++) af[mt]  = *(const short8*)&Asb[(mt*16 + l15)*40 + quad*8];
    #pragma unroll
    for (int gt=0;gt<4;gt++) bfr[gt] = *(const short8*)&Bsb[(w*64 + gt*16 + l15)*40 + quad*8];
    #pragma unroll
    for (int mt=0;mt<4;mt++)
      #pragma unroll
      for (int gt=0;gt<4;gt++)
        acc[mt][gt] = __builtin_amdgcn_mfma_f32_16x16x32_bf16(af[mt], bfr[gt], acc[mt][gt], 0,0,0);
  }

  float sp[16];
  #pragma unroll
  for (int i=0;i<16;i++) sp[i]=0.f;
  #pragma unroll
  for (int gt=0;gt<4;gt++){
    int g = g0 + w*64 + gt*16 + l15;
    float vg = vattn[g];
    #pragma unroll
    for (int mt=0;mt<4;mt++){
      #pragma unroll
      for (int r=0;r<4;r++){
        int b = mt*16 + quad*4 + r;
        float val = acc[mt][gt][r] + hWh[b*1024 + g];
        sp[mt*4+r] = fmaf(vg, fast_tanh(val), sp[mt*4+r]);
      }
    }
  }
  #pragma unroll
  for (int off=1; off<16; off<<=1){
    #pragma unroll
    for (int i=0;i<16;i++) sp[i] += __shfl_xor(sp[i], off);
  }
  if (l15 == 0){
    #pragma unroll
    for (int mt=0;mt<4;mt++)
      #pragma unroll
      for (int r=0;r<4;r++){
        int b = mt*16 + quad*4 + r;
        atomicAdd(&scoresT[s*64 + b], sp[mt*4+r]);
      }
  }
}

// ---------------- vocab GEMM: out[b][n] = concat[b] . W_out[n] + b_out[n], MFMA bf16 ----------------
// A = concat [64][1024] fp32 row-major; W = W_out [V][1024] fp32. fp32->bf16 in-register.
__launch_bounds__(256, 2)
__global__ void vocab_gemm_kernel(const float* __restrict__ A, const float* __restrict__ W,
                                  const float* __restrict__ bias, float* __restrict__ out)
{
  __shared__ unsigned short Asb[64*40];
  __shared__ unsigned short Bsb[256*40];
  int tid = threadIdx.x;
  int n0 = blockIdx.x * 256;
  int l = tid & 63, w = tid >> 6;
  int quad = l >> 4, l15 = l & 15;

  int arow = tid >> 2, aq = tid & 3;   // A staging: 64 rows x 32 k
  int bkq = tid & 7;                   // B staging: 8 threads per row (float4 each)
  int brow = tid >> 3;                 // 32 rows per pass, 8 passes

  f32x4 acc[4][4];
  #pragma unroll
  for (int mt=0;mt<4;mt++)
    #pragma unroll
    for (int gt=0;gt<4;gt++) acc[mt][gt] = 0.f;

  for (int kt=0; kt<32; kt++){
    __syncthreads();
    {
      // stage A: fp32 -> bf16
      const float4* ap = (const float4*)&A[arow*1024 + kt*32 + aq*8];
      float4 f0 = ap[0], f1 = ap[1];
      uint4 p;
      p.x = bfpack(f0.x, f0.y); p.y = bfpack(f0.z, f0.w);
      p.z = bfpack(f1.x, f1.y); p.w = bfpack(f1.z, f1.w);
      *(uint4*)&Asb[arow*40 + aq*8] = p;
      // stage B: 256 rows x 32 k fp32 -> bf16, coalesced float4 per thread, 8 passes
      #pragma unroll
      for (int p4=0;p4<8;p4++){
        int row = p4*32 + brow;
        int gr = n0 + row; if (gr >= Vn) gr = Vn-1;
        float4 f = *(const float4*)&W[(long)gr*1024 + kt*32 + bkq*4];
        uint2 q; q.x = bfpack(f.x, f.y); q.y = bfpack(f.z, f.w);
        *(uint2*)&Bsb[row*40 + bkq*4] = q;
      }
    }
    __syncthreads();
    short8 af[4], bfr[4];
    #pragma unroll
    for (int mt=0;mt<4;mt++) af[mt]  = *(const short8*)&Asb[(mt*16 + l15)*40 + quad*8];
    #pragma unroll
    for (int gt=0;gt<4;gt++) bfr[gt] = *(const short8*)&Bsb[(w*64 + gt*16 + l15)*40 + quad*8];
    #pragma unroll
    for (int mt=0;mt<4;mt++)
      #pragma unroll
      for (int gt=0;gt<4;gt++)
        acc[mt][gt] = __builtin_amdgcn_mfma_f32_16x16x32_bf16(af[mt], bfr[gt], acc[mt][gt], 0,0,0);
  }

  // epilogue: out[b][n] = acc + bias[n]
  #pragma unroll
  for (int gt=0;gt<4;gt++){
    int n = n0 + w*64 + gt*16 + l15;
    if (n >= Vn) continue;
    float bz = bias[n];
    #pragma unroll
    for (int mt=0;mt<4;mt++){
      #pragma unroll
      for (int r=0;r<4;r++){
        int b = mt*16 + quad*4 + r;
        out[(long)b*Vn + n] = acc[mt][gt][r] + bz;
      }
    }
  }
}

// ---------------- softmax over b (axis=0) per s, apply mask ----------------
__global__ void softmax_b_kernel(float* __restrict__ a_sb, const float* __restrict__ mask){
  int tid = threadIdx.x; int l = tid & 63; int w = tid >> 6;
  int s = blockIdx.x*4 + w;
  float x = a_sb[s*64 + l];
  float m = x;
  #pragma unroll
  for (int off=1; off<64; off<<=1) m = fmaxf(m, __shfl_xor(m, off));
  float e = fast_exp2((x - m)*1.4426950408889634f);
  float t = e;
  #pragma unroll
  for (int off=1; off<64; off<<=1) t += __shfl_xor(t, off);
  float a = e * fast_rcp(t);
  a *= mask[s*64 + l];
  a_sb[s*64 + l] = a;
}

// ---------------- normalize over s per b; write alpha and aBS ----------------
__global__ void norm_s_kernel(const float* __restrict__ a_sb, float* __restrict__ aBS,
                              float* __restrict__ alpha){
  int b = blockIdx.x; int l = threadIdx.x;
  float tot = 0.f;
  #pragma unroll
  for (int i=0;i<8;i++) tot += a_sb[(l + i*64)*64 + b];
  #pragma unroll
  for (int off=1; off<64; off<<=1) tot += __shfl_xor(tot, off);
  float inv = 1.0f/(tot + 1e-10f);
  #pragma unroll
  for (int i=0;i<8;i++){
    int sidx = l + i*64;
    float v = a_sb[sidx*64 + b]*inv;
    aBS[b*512 + sidx] = v;
    alpha[b*512 + sidx] = v;
  }
}

// ---------------- context[b][h] = sum_s a[b][s]*enc[s][b][h] ----------------
__global__ void context_kernel(const float* __restrict__ aBS, const float* __restrict__ enc,
                               float* __restrict__ ctx_out, float* __restrict__ ctxT4){
  int h = blockIdx.x*256 + threadIdx.x;
  int b = blockIdx.y;
  const float* ab = aBS + b*512;
  float acc = 0.f;
  for (int s0=0; s0<512; s0+=16){
    float av[16], ev[16];
    #pragma unroll
    for (int i=0;i<16;i++) av[i] = ab[s0+i];
    #pragma unroll
    for (int i=0;i<16;i++) ev[i] = enc[((long)(s0+i)*64 + b)*1024 + h];
    #pragma unroll
    for (int i=0;i<16;i++) acc = fmaf(av[i], ev[i], acc);
  }
  ctx_out[b*1024 + h] = acc;
  ctxT4[(h>>2)*256 + b*4 + (h&3)] = acc;
}

extern "C" void kernel_launch(void* const* d_in, const int* in_sizes, int n_in,
                              void* d_out, int out_size, void* d_ws, size_t ws_size,
                              hipStream_t stream)
{
  const int*   idx    = (const int*)  d_in[0];
  const float* h0     = (const float*)d_in[2];
  const float* c0     = (const float*)d_in[3];
  const float* enc    = (const float*)d_in[4];
  const float* mask   = (const float*)d_in[5];
  const float* emb    = (const float*)d_in[6];
  const float* W_ih   = (const float*)d_in[7];
  const float* W_hh   = (const float*)d_in[8];
  const float* b_ih   = (const float*)d_in[9];
  const float* b_hh   = (const float*)d_in[10];
  const float* W_attn = (const float*)d_in[11];
  const float* v_attn = (const float*)d_in[12];
  const float* W_cat  = (const float*)d_in[13];
  const float* b_cat  = (const float*)d_in[14];
  const float* W_out  = (const float*)d_in[15];
  const float* b_out  = (const float*)d_in[16];

  float* out     = (float*)d_out;
  float* o_ctx   = out + (long)Bn*Vn;
  float* o_h     = o_ctx + Bn*Hn;
  float* o_c     = o_h + Bn*Hn;
  float* o_alpha = o_c + Bn*Hn;

  float* ws    = (float*)d_ws;
  float* xT4   = ws;               // 65536
  float* hT4   = xT4 + 65536;      // 65536
  float* gates = hT4 + 65536;      // 262144
  float* hnT4  = gates + 262144;   // 65536
  float* hWh   = hnT4 + 65536;     // 65536
  float* a_sb  = hWh + 65536;      // 32768
  float* aBS   = a_sb + 32768;     // 32768
  float* ctxT4 = aBS + 32768;      // 65536
  float* catRM = ctxT4 + 65536;    // 65536 (concat, row-major [64][1024])
  unsigned short* we_bf = (unsigned short*)(catRM + 65536); // 1M bf16 = 2 MB

  prep_kernel<<<64,256,0,stream>>>(idx, (const float4*)emb, (const float4*)h0,
                                   (float4*)xT4, (float4*)hT4);
  conv_we_kernel<<<1024,256,0,stream>>>(W_attn, we_bf);
  zero_kernel<<<128,256,0,stream>>>(a_sb, 32768);
  skinny_gemm<4,2,false,false><<<256,256,0,stream>>>((const float4*)xT4, W_ih, 1024,
      (const float4*)hT4, W_hh, 1024, 0, b_ih, b_hh, gates, 4096, 4096, 256);
  lstm_kernel<<<256,256,0,stream>>>(gates, c0, o_h, o_c, hnT4);
  skinny_gemm<4,1,false,false><<<64,256,0,stream>>>((const float4*)hnT4, W_attn, 2048,
      nullptr, nullptr, 0, 0, nullptr, nullptr, hWh, 1024, 1024, 256);
  attn_scores_kernel<<<2048,256,0,stream>>>((const float4*)enc, we_bf, hWh, v_attn, a_sb);
  softmax_b_kernel<<<128,256,0,stream>>>(a_sb, mask);
  norm_s_kernel<<<64,64,0,stream>>>(a_sb, aBS, o_alpha);
  context_kernel<<<dim3(4,64),256,0,stream>>>(aBS, enc, o_ctx, ctxT4);
  // concat = tanh(h@Wc1^T + ctx@Wc2^T + b_cat), row-major [64][1024]
  skinny_gemm<4,2,true,false><<<64,256,0,stream>>>((const float4*)hnT4, W_cat, 2048,
      (const float4*)ctxT4, W_cat, 2048, 1024, b_cat, nullptr, catRM, 1024, 1024, 256);
  // output = concat@W_out^T + b_out  (MFMA bf16, W fetched once coalesced)
  vocab_gemm_kernel<<<197,256,0,stream>>>(catRM, W_out, b_out, out);
}